// Round 5
// baseline (269.092 us; speedup 1.0000x reference)
//
#include <hip/hip_runtime.h>

typedef __attribute__((ext_vector_type(8))) short short8;
typedef __attribute__((ext_vector_type(4))) float floatx4;
typedef __attribute__((ext_vector_type(2))) unsigned int uint32x2;
typedef __attribute__((ext_vector_type(4))) unsigned int uint32x4;
typedef unsigned short u16;

#define LOG2E 1.4426950408889634f

#if __has_builtin(__builtin_amdgcn_exp2f)
#define EXP2(x) __builtin_amdgcn_exp2f(x)
#else
#define EXP2(x) exp2f(x)
#endif

static __device__ __forceinline__ u16 f2bf(float f){
  unsigned int u = __builtin_bit_cast(unsigned int, f);
  u += 0x7fffu + ((u >> 16) & 1u);
  return (u16)(u >> 16);
}

static __device__ __forceinline__ unsigned int cvtpk(float lo, float hi){
  unsigned int r;
  asm("v_cvt_pk_bf16_f32 %0, %1, %2" : "=v"(r) : "v"(lo), "v"(hi));
  return r;
}

static __device__ __forceinline__ void gload16(const void* g, void* l){
  __builtin_amdgcn_global_load_lds((__attribute__((address_space(1))) void*)(g),
                                   (__attribute__((address_space(3))) void*)(l),
                                   16, 0, 0);
}

// ---------------- fused cast f32 -> bf16 (7 segments, one launch) ----------------
struct CastSeg { const float* src; u16* dst; int n8; float scale; };
struct Cast7 { CastSeg s[7]; };

__global__ __launch_bounds__(256) void k_cast_all(Cast7 a){
  #pragma unroll 1
  for (int si = 0; si < 7; ++si){
    const float* __restrict__ src = a.s[si].src;
    u16* __restrict__ dst = a.s[si].dst;
    const int n8 = a.s[si].n8;
    const float sc = a.s[si].scale;
    for (int i = blockIdx.x * 256 + threadIdx.x; i < n8; i += gridDim.x * 256){
      const float4* p = (const float4*)(src + (size_t)i * 8);
      float4 x = p[0], y = p[1];
      short8 r;
      r[0] = (short)f2bf(x.x * sc); r[1] = (short)f2bf(x.y * sc);
      r[2] = (short)f2bf(x.z * sc); r[3] = (short)f2bf(x.w * sc);
      r[4] = (short)f2bf(y.x * sc); r[5] = (short)f2bf(y.y * sc);
      r[6] = (short)f2bf(y.z * sc); r[7] = (short)f2bf(y.w * sc);
      *(short8*)(dst + (size_t)i * 8) = r;
    }
  }
}

// ------------- GEMM body: C[M,N] = A[M,K] @ W[N,K]^T  (bf16 in, bf16/f32 out) -------------
// BNFR=2: BM=128,BN=64 (wave 64x32, acc 4x2).  BNFR=4: BM=128,BN=128 (wave 64x64, acc 4x4, m97 tile).
template<int OUTF32, int BNFR>
static __device__ __forceinline__ void gemm_body(const u16* __restrict__ A, const u16* __restrict__ W,
                                                 void* __restrict__ C, int M, int N, int K, int nb){
  __shared__ u16 As[128 * 32];
  __shared__ u16 Bs[BNFR * 32 * 32];
  const int tid = threadIdx.x, lane = tid & 63, w = tid >> 6;
  const int nt = (BNFR == 4) ? (N >> 7) : (N >> 6);
  const int bm = nb / nt, bn = nb % nt;
  const int wr = w >> 1, wc = w & 1;
  const int BN = BNFR * 32;

  const int srow = lane >> 2, scol = (lane & 3) * 8;
  const u16* Ag0 = A + (size_t)(bm * 128 +      w * 16 + srow) * K + scol;
  const u16* Ag1 = A + (size_t)(bm * 128 + 64 + w * 16 + srow) * K + scol;
  const u16* Wg0 = W + (size_t)(bn * BN +       w * 16 + srow) * K + scol;
  const u16* Wg1 = W + (size_t)(bn * BN + 64 +  w * 16 + srow) * K + scol; // BNFR==4 only
  u16* As0 = &As[w * 512];
  u16* As1 = &As[2048 + w * 512];
  u16* Bs0 = &Bs[w * 512];
  u16* Bs1 = &Bs[2048 + w * 512];

  floatx4 acc[4][BNFR];
  #pragma unroll
  for (int i = 0; i < 4; ++i)
    #pragma unroll
    for (int j = 0; j < BNFR; ++j) acc[i][j] = (floatx4){0.f, 0.f, 0.f, 0.f};

  const int arow = wr * 64 + (lane & 15);
  const int brow = wc * (BNFR * 16) + (lane & 15);
  const int kcol = (lane >> 4) * 8;

  for (int k0 = 0; k0 < K; k0 += 32){
    __syncthreads();
    gload16(Ag0, As0);
    gload16(Ag1, As1);
    gload16(Wg0, Bs0);
    if (BNFR == 4) gload16(Wg1, Bs1);
    Ag0 += 32; Ag1 += 32; Wg0 += 32; Wg1 += 32;
    __syncthreads();
    short8 bf[BNFR];
    #pragma unroll
    for (int ni = 0; ni < BNFR; ++ni)
      bf[ni] = *(const short8*)&Bs[(brow + ni * 16) * 32 + kcol];
    #pragma unroll
    for (int mi = 0; mi < 4; ++mi){
      short8 af = *(const short8*)&As[(arow + mi * 16) * 32 + kcol];
      #pragma unroll
      for (int ni = 0; ni < BNFR; ++ni)
        acc[mi][ni] = __builtin_amdgcn_mfma_f32_16x16x32_bf16(af, bf[ni], acc[mi][ni], 0, 0, 0);
    }
  }

  const int crow = bm * 128 + wr * 64 + (lane >> 4) * 4;
  const int ccol = bn * BN + wc * (BNFR * 16) + (lane & 15);
  #pragma unroll
  for (int mi = 0; mi < 4; ++mi)
    #pragma unroll
    for (int ni = 0; ni < BNFR; ++ni)
      #pragma unroll
      for (int r = 0; r < 4; ++r){
        size_t idx = (size_t)(crow + mi * 16 + r) * N + ccol + ni * 16;
        if (OUTF32) ((float*)C)[idx] = acc[mi][ni][r];
        else        ((u16*)C)[idx]   = f2bf(acc[mi][ni][r]);
      }
}

// fused projections: 1280 blocks; 1-in-5 interleave -> qh (256 blocks), rest -> khv (1024 blocks)
__global__ __launch_bounds__(256) void k_proj(const u16* __restrict__ q_bf, const u16* __restrict__ wq_b,
                                              u16* __restrict__ qh, const u16* __restrict__ c_bf,
                                              const u16* __restrict__ wkv, u16* __restrict__ khv){
  const int sw = (blockIdx.x & 7) * 160 + (blockIdx.x >> 3);   // XCD swizzle over 1280
  const int d5 = sw / 5;
  if (sw - d5 * 5 == 0) gemm_body<0, 4>(q_bf, wq_b, qh, 4096, 1024, 1024, d5);
  else                  gemm_body<0, 4>(c_bf, wkv, khv, 8192, 2048, 1024, sw - 1 - d5);
}

// standalone GEMM (output projection)
template<int OUTF32, int BNFR>
__global__ __launch_bounds__(256) void k_gemm_bt(const u16* __restrict__ A, const u16* __restrict__ W,
                                                 void* __restrict__ C, int M, int N, int K){
  const int nb = (blockIdx.x & 7) * (gridDim.x >> 3) + (blockIdx.x >> 3);
  gemm_body<OUTF32, BNFR>(A, W, C, M, N, K, nb);
}

// ------------- vh rows (t*2+b) stride rs -> vhT [(b*16+h)*64+d][4096 t] -------------
__global__ __launch_bounds__(256) void k_transpose_v(const u16* __restrict__ vh, int rs,
                                                     u16* __restrict__ vhT){
  __shared__ u16 Ts[64 * 64];
  const int bid = blockIdx.x;
  const int tt = bid & 63;
  const int ot = (bid >> 6) & 15;
  const int b  = bid >> 10;
  const int tid = threadIdx.x;

  #pragma unroll
  for (int it = 0; it < 2; ++it){
    int li = tid + it * 256;
    int rt = li >> 3, c8 = li & 7;
    short8 v = *(const short8*)&vh[(size_t)((tt * 64 + rt) * 2 + b) * rs + ot * 64 + c8 * 8];
    int byteoff = (rt * 128 + c8 * 16) ^ ((rt & 7) << 4);
    *(short8*)((char*)Ts + byteoff) = v;
  }
  __syncthreads();

  const int ro = tid & 63, cg = tid >> 6;
  short8 x0, x1;
  #pragma unroll
  for (int tj = 0; tj < 8; ++tj){
    int trow = cg * 16 + tj;
    x0[tj] = (short)*(const u16*)((char*)Ts + ((trow * 128 + ro * 2) ^ ((trow & 7) << 4)));
  }
  #pragma unroll
  for (int tj = 0; tj < 8; ++tj){
    int trow = cg * 16 + 8 + tj;
    x1[tj] = (short)*(const u16*)((char*)Ts + ((trow * 128 + ro * 2) ^ ((trow & 7) << 4)));
  }
  u16* dst = &vhT[(size_t)(b * 1024 + ot * 64 + ro) * 4096 + tt * 64 + cg * 16];
  *(short8*)dst       = x0;
  *(short8*)(dst + 8) = x1;
}

// ------------- flash attention: 8 waves (qi,kj), CHUNK=128 keys, double-buffered LDS -------------
// qh[4096][1024] (pre-scaled by 0.125*log2e), kh rows (t*2+b) stride 2048 (cols 0..1023 of khv),
// vt[2048][4096] -> av[4096][1024]
// Wave (qi = w&3, kj = w>>2): 32 q-rows x 64-key half of each 128-key chunk.
// S^T = mfma(K, Q); P^T -> PV B-frags via permlane32/16_swap; no-max softmax, additive across kj.
// Double buffer: ONE barrier per chunk; stage-writes(ch+1) + global loads(ch+2) overlap compute(ch).
__global__ __launch_bounds__(512, 4) void k_attn(const u16* __restrict__ qh, const u16* __restrict__ kh,
                                                 const u16* __restrict__ vt, u16* __restrict__ av){
  // buf p (32 KB each): Ks [128k][64d] at byte 0; Vs [64d][128k] at byte 16384
  __shared__ __align__(16) u16 smem[2 * 16384];
  __shared__ float LsX[4][2][64];
  const int tid = threadIdx.x, lane = tid & 63, w = tid >> 6;
  const int qi = w & 3, kj = w >> 2;
  const int g = lane >> 4, q = lane & 15;
  const int nb = (blockIdx.x & 7) * 64 + (blockIdx.x >> 3);  // XCD swizzle (512 blocks)
  const int bh = nb >> 4, qt = nb & 15;
  const int b = bh >> 4, h = bh & 15;

  // Q as B-operand: lane holds col q, dh = kk*32 + g*8 + e
  short8 qf[2][2];
  #pragma unroll
  for (int rf = 0; rf < 2; ++rf){
    int row_l = qt * 128 + qi * 32 + rf * 16 + q;
    #pragma unroll
    for (int kk = 0; kk < 2; ++kk)
      qf[rf][kk] = *(const short8*)&qh[(size_t)(row_l * 2 + b) * 1024 + h * 64 + kk * 32 + g * 8];
  }

  floatx4 o[2][4];
  #pragma unroll
  for (int rf = 0; rf < 2; ++rf)
    #pragma unroll
    for (int dj = 0; dj < 4; ++dj) o[rf][dj] = (floatx4){0.f, 0.f, 0.f, 0.f};
  float ls0 = 0.f, ls1 = 0.f;

  // hoisted swizzled byte offsets (within a buf)
  // K read: row jr = kj*64 + t4*16 + q (128B rows, XOR (q&7)<<4)
  // V read: row dr = t4*16 + q (256B rows at byte 16384+, XOR q<<4)
  int offA[4][2], offB[4][2];
  #pragma unroll
  for (int t4 = 0; t4 < 4; ++t4)
    #pragma unroll
    for (int kk = 0; kk < 2; ++kk){
      offA[t4][kk] = kj * 8192 + (((t4 * 16 + q) * 128 + kk * 64 + g * 16) ^ ((q & 7) << 4));
      offB[t4][kk] = 16384 + (((t4 * 16 + q) * 256 + kj * 128 + kk * 64 + g * 16) ^ (q << 4));
    }

  // staging maps (all 512 threads)
  const int krow = tid >> 3, kc8 = tid & 7;    // K: rows krow, krow+64
  const int vrow = tid >> 4, vc16 = tid & 15;  // V: rows vrow, vrow+32
  const int kwb0 = (((krow)      * 128 + kc8 * 16) ^ ((krow & 7) << 4));
  const int kwb1 = (((krow + 64) * 128 + kc8 * 16) ^ ((krow & 7) << 4));
  const int vwb0 = 16384 + (((vrow)      * 256 + vc16 * 16) ^ ((vrow & 15) << 4));
  const int vwb1 = 16384 + (((vrow + 32) * 256 + vc16 * 16) ^ ((vrow & 15) << 4));
  const u16* kg = kh + (size_t)b * 2048 + h * 64 + kc8 * 8;   // t stride = 4096 u16
  const u16* vg = vt + (size_t)(bh * 64) * 4096 + vc16 * 8;

  // prologue: chunk 0 -> buf0; chunk 1 -> regs
  short8 ka0 = *(const short8*)(kg + (size_t)(krow)      * 4096);
  short8 ka1 = *(const short8*)(kg + (size_t)(krow + 64) * 4096);
  short8 va0 = *(const short8*)(vg + (size_t)(vrow)      * 4096);
  short8 va1 = *(const short8*)(vg + (size_t)(vrow + 32) * 4096);
  {
    char* b0 = (char*)smem;
    *(short8*)(b0 + kwb0) = ka0;
    *(short8*)(b0 + kwb1) = ka1;
    *(short8*)(b0 + vwb0) = va0;
    *(short8*)(b0 + vwb1) = va1;
  }
  ka0 = *(const short8*)(kg + (size_t)(128 + krow)      * 4096);
  ka1 = *(const short8*)(kg + (size_t)(128 + krow + 64) * 4096);
  va0 = *(const short8*)(vg + (size_t)(vrow)      * 4096 + 128);
  va1 = *(const short8*)(vg + (size_t)(vrow + 32) * 4096 + 128);
  __syncthreads();

  for (int ch = 0; ch < 32; ++ch){
    const int base = (ch & 1) << 15;
    const char* bp = (const char*)smem + base;
    char* bq = (char*)smem + (base ^ 32768);

    // K frags first (QK won't wait on the stage-writes below: ds FIFO order)
    short8 kf[4][2];
    #pragma unroll
    for (int cj = 0; cj < 4; ++cj)
      #pragma unroll
      for (int kk = 0; kk < 2; ++kk)
        kf[cj][kk] = *(const short8*)(bp + offA[cj][kk]);

    // stage chunk ch+1 into the other buffer (safe: barrier at end of ch-1)
    if (ch < 31){
      *(short8*)(bq + kwb0) = ka0;
      *(short8*)(bq + kwb1) = ka1;
      *(short8*)(bq + vwb0) = va0;
      *(short8*)(bq + vwb1) = va1;
    }

    // S^T = K @ Q
    floatx4 st[2][4];
    #pragma unroll
    for (int rf = 0; rf < 2; ++rf)
      #pragma unroll
      for (int cj = 0; cj < 4; ++cj) st[rf][cj] = (floatx4){0.f, 0.f, 0.f, 0.f};
    __builtin_amdgcn_s_setprio(1);
    #pragma unroll
    for (int cj = 0; cj < 4; ++cj)
      #pragma unroll
      for (int kk = 0; kk < 2; ++kk){
        st[0][cj] = __builtin_amdgcn_mfma_f32_16x16x32_bf16(kf[cj][kk], qf[0][kk], st[0][cj], 0, 0, 0);
        st[1][cj] = __builtin_amdgcn_mfma_f32_16x16x32_bf16(kf[cj][kk], qf[1][kk], st[1][cj], 0, 0, 0);
      }
    __builtin_amdgcn_s_setprio(0);

    // issue global loads for chunk ch+2 (latency spans softmax+PV+next QK)
    if (ch < 30){
      const size_t t2 = (size_t)(ch + 2) * 128;
      ka0 = *(const short8*)(kg + (t2 + krow)      * 4096);
      ka1 = *(const short8*)(kg + (t2 + krow + 64) * 4096);
      va0 = *(const short8*)(vg + (size_t)(vrow)      * 4096 + t2);
      va1 = *(const short8*)(vg + (size_t)(vrow + 32) * 4096 + t2);
    }

    // no-max softmax: P = exp2(S), per-lane partial sums; pack bf16 pairs
    unsigned int xw[2][4][2];
    #pragma unroll
    for (int rf = 0; rf < 2; ++rf){
      float rs = 0.f;
      #pragma unroll
      for (int cj = 0; cj < 4; ++cj){
        float p0 = EXP2(st[rf][cj][0]);
        float p1 = EXP2(st[rf][cj][1]);
        float p2 = EXP2(st[rf][cj][2]);
        float p3 = EXP2(st[rf][cj][3]);
        rs += (p0 + p1) + (p2 + p3);
        xw[rf][cj][0] = cvtpk(p0, p1);
        xw[rf][cj][1] = cvtpk(p2, p3);
      }
      if (rf == 0) ls0 += rs; else ls1 += rs;
    }

    // register P^T exchange -> PV B-frags (lane&15 preserved)
    uint32x4 pb[2][2];
    #pragma unroll
    for (int rf = 0; rf < 2; ++rf)
      #pragma unroll
      for (int kk = 0; kk < 2; ++kk)
        #pragma unroll
        for (int wd = 0; wd < 2; ++wd){
          unsigned int aa = xw[rf][2 * kk][wd], bb = xw[rf][2 * kk + 1][wd];
          asm("v_permlane32_swap_b32 %0, %1" : "+v"(aa), "+v"(bb));
          asm("v_permlane16_swap_b32 %0, %1" : "+v"(aa), "+v"(bb));
          pb[rf][kk][wd]     = aa;
          pb[rf][kk][wd + 2] = bb;
        }

    // O^T += V^T @ P^T
    __builtin_amdgcn_s_setprio(1);
    #pragma unroll
    for (int kk = 0; kk < 2; ++kk){
      short8 pb0 = __builtin_bit_cast(short8, pb[0][kk]);
      short8 pb1 = __builtin_bit_cast(short8, pb[1][kk]);
      #pragma unroll
      for (int dj = 0; dj < 4; ++dj){
        short8 vf = *(const short8*)(bp + offB[dj][kk]);
        o[0][dj] = __builtin_amdgcn_mfma_f32_16x16x32_bf16(vf, pb0, o[0][dj], 0, 0, 0);
        o[1][dj] = __builtin_amdgcn_mfma_f32_16x16x32_bf16(vf, pb1, o[1][dj], 0, 0, 0);
      }
    }
    __builtin_amdgcn_s_setprio(0);

    __syncthreads();   // single barrier per chunk
  }

  // combine kj halves: partial O and l are directly additive (no-max softmax)
  if (kj == 1){
    #pragma unroll
    for (int rf = 0; rf < 2; ++rf)
      #pragma unroll
      for (int dj = 0; dj < 4; ++dj){
        int idx = rf * 4 + dj;
        *(floatx4*)((char*)smem + qi * 8192 + ((lane * 128 + idx * 16) ^ ((lane & 7) << 4))) = o[rf][dj];
      }
    LsX[qi][0][lane] = ls0;
    LsX[qi][1][lane] = ls1;
  }
  __syncthreads();
  if (kj == 0){
    #pragma unroll
    for (int rf = 0; rf < 2; ++rf)
      #pragma unroll
      for (int dj = 0; dj < 4; ++dj){
        int idx = rf * 4 + dj;
        o[rf][dj] += *(const floatx4*)((char*)smem + qi * 8192 + ((lane * 128 + idx * 16) ^ ((lane & 7) << 4)));
      }
    ls0 += LsX[qi][0][lane];
    ls1 += LsX[qi][1][lane];
    ls0 += __shfl_xor(ls0, 16, 64);
    ls0 += __shfl_xor(ls0, 32, 64);
    ls1 += __shfl_xor(ls1, 16, 64);
    ls1 += __shfl_xor(ls1, 32, 64);
    #pragma unroll
    for (int rf = 0; rf < 2; ++rf){
      float inv = 1.0f / (rf == 0 ? ls0 : ls1);
      int row_l = qt * 128 + qi * 32 + rf * 16 + q;
      u16* dst = av + (size_t)(row_l * 2 + b) * 1024 + h * 64 + 4 * g;
      #pragma unroll
      for (int dj = 0; dj < 4; ++dj){
        uint32x2 pk;
        pk[0] = cvtpk(o[rf][dj][0] * inv, o[rf][dj][1] * inv);
        pk[1] = cvtpk(o[rf][dj][2] * inv, o[rf][dj][3] * inv);
        *(uint32x2*)(dst + dj * 16) = pk;
      }
    }
  }
}

// --------------------------------- launch ---------------------------------
extern "C" void kernel_launch(void* const* d_in, const int* in_sizes, int n_in,
                              void* d_out, int out_size, void* d_ws, size_t ws_size,
                              hipStream_t stream){
  const float* q    = (const float*)d_in[0];
  const float* kv   = (const float*)d_in[1];
  const float* mems = (const float*)d_in[2];
  const float* wq   = (const float*)d_in[3];
  const float* wk   = (const float*)d_in[4];
  const float* wv   = (const float*)d_in[5];
  const float* wc   = (const float*)d_in[6];

  const size_t SZ_Q  = (size_t)4096 * 1024;   // L*B x D
  const size_t SZ_C  = (size_t)8192 * 1024;   // (M+L)*B x D
  const size_t SZ_W  = (size_t)1024 * 1024;
  const size_t SZ_KV = (size_t)8192 * 2048;   // fused K|V projection output

  u16* ws   = (u16*)d_ws;
  u16* q_bf = ws;                 // later reused as attn_vec (av)
  u16* c_bf = q_bf + SZ_Q;        // later reused as vhT (8M elem: exact fit)
  u16* wq_b = c_bf + SZ_C;
  u16* wk_b = wq_b + SZ_W;        // wk_b and wv_b adjacent -> fused W_kv [2048][1024]
  u16* wv_b = wk_b + SZ_W;
  u16* wc_b = wv_b + SZ_W;
  u16* qh   = wc_b + SZ_W;
  u16* khv  = qh + SZ_Q;          // [8192][2048]: cols 0..1023 = kh, 1024..2047 = vh

  // fused casts; attention scale 1/8 AND log2e folded into w_q
  Cast7 ca;
  ca.s[0] = { q,    q_bf,        (int)(SZ_Q / 8), 1.0f };
  ca.s[1] = { mems, c_bf,        (int)(SZ_Q / 8), 1.0f };
  ca.s[2] = { kv,   c_bf + SZ_Q, (int)(SZ_Q / 8), 1.0f };
  ca.s[3] = { wq,   wq_b,        (int)(SZ_W / 8), 0.125f * LOG2E };
  ca.s[4] = { wk,   wk_b,        (int)(SZ_W / 8), 1.0f };
  ca.s[5] = { wv,   wv_b,        (int)(SZ_W / 8), 1.0f };
  ca.s[6] = { wc,   wc_b,        (int)(SZ_W / 8), 1.0f };
  k_cast_all<<<2048, 256, 0, stream>>>(ca);

  // fused projections: q -> qh AND c -> [kh | vh], one 1280-block launch (128^2 tiles)
  k_proj<<<1280, 256, 0, stream>>>(q_bf, wq_b, qh, c_bf, wk_b, khv);

  // V part of khv -> vhT [(b*16+h)*64+d][t]
  k_transpose_v<<<2048, 256, 0, stream>>>(khv + 1024, 2048, c_bf);

  // flash attention -> av (8 waves: 4 q-subtiles x 2 key-halves, double-buffered)
  k_attn<<<512, 512, 0, stream>>>(qh, khv, c_bf, q_bf);

  // out = attn_vec @ w_concat^T  (fp32 out)
  k_gemm_bt<1, 2><<<512, 256, 0, stream>>>(q_bf, wc_b, d_out, 4096, 1024, 1024);
}

// Round 6
// 198.013 us; speedup vs baseline: 1.3590x; 1.3590x over previous
//
#include <hip/hip_runtime.h>

typedef __attribute__((ext_vector_type(8))) short short8;
typedef __attribute__((ext_vector_type(4))) float floatx4;
typedef __attribute__((ext_vector_type(2))) unsigned int uint32x2;
typedef __attribute__((ext_vector_type(4))) unsigned int uint32x4;
typedef unsigned short u16;

#define LOG2E 1.4426950408889634f

#if __has_builtin(__builtin_amdgcn_exp2f)
#define EXP2(x) __builtin_amdgcn_exp2f(x)
#else
#define EXP2(x) exp2f(x)
#endif

static __device__ __forceinline__ u16 f2bf(float f){
  unsigned int u = __builtin_bit_cast(unsigned int, f);
  u += 0x7fffu + ((u >> 16) & 1u);
  return (u16)(u >> 16);
}

static __device__ __forceinline__ unsigned int cvtpk(float lo, float hi){
  unsigned int r;
  asm("v_cvt_pk_bf16_f32 %0, %1, %2" : "=v"(r) : "v"(lo), "v"(hi));
  return r;
}

static __device__ __forceinline__ void gload16(const void* g, void* l){
  __builtin_amdgcn_global_load_lds((__attribute__((address_space(1))) void*)(g),
                                   (__attribute__((address_space(3))) void*)(l),
                                   16, 0, 0);
}

// ---------------- fused cast f32 -> bf16 (7 segments, one launch) ----------------
struct CastSeg { const float* src; u16* dst; int n8; float scale; };
struct Cast7 { CastSeg s[7]; };

__global__ __launch_bounds__(256) void k_cast_all(Cast7 a){
  #pragma unroll 1
  for (int si = 0; si < 7; ++si){
    const float* __restrict__ src = a.s[si].src;
    u16* __restrict__ dst = a.s[si].dst;
    const int n8 = a.s[si].n8;
    const float sc = a.s[si].scale;
    for (int i = blockIdx.x * 256 + threadIdx.x; i < n8; i += gridDim.x * 256){
      const float4* p = (const float4*)(src + (size_t)i * 8);
      float4 x = p[0], y = p[1];
      short8 r;
      r[0] = (short)f2bf(x.x * sc); r[1] = (short)f2bf(x.y * sc);
      r[2] = (short)f2bf(x.z * sc); r[3] = (short)f2bf(x.w * sc);
      r[4] = (short)f2bf(y.x * sc); r[5] = (short)f2bf(y.y * sc);
      r[6] = (short)f2bf(y.z * sc); r[7] = (short)f2bf(y.w * sc);
      *(short8*)(dst + (size_t)i * 8) = r;
    }
  }
}

// ------------- GEMM body: C[M,N] = A[M,K] @ W[N,K]^T  (bf16 in, bf16/f32 out) -------------
// BNFR=2: BM=128,BN=64 (wave 64x32, acc 4x2).  BNFR=4: BM=128,BN=128 (wave 64x64, acc 4x4, m97 tile).
template<int OUTF32, int BNFR>
static __device__ __forceinline__ void gemm_body(const u16* __restrict__ A, const u16* __restrict__ W,
                                                 void* __restrict__ C, int M, int N, int K, int nb){
  __shared__ u16 As[128 * 32];
  __shared__ u16 Bs[BNFR * 32 * 32];
  const int tid = threadIdx.x, lane = tid & 63, w = tid >> 6;
  const int nt = (BNFR == 4) ? (N >> 7) : (N >> 6);
  const int bm = nb / nt, bn = nb % nt;
  const int wr = w >> 1, wc = w & 1;
  const int BN = BNFR * 32;

  const int srow = lane >> 2, scol = (lane & 3) * 8;
  const u16* Ag0 = A + (size_t)(bm * 128 +      w * 16 + srow) * K + scol;
  const u16* Ag1 = A + (size_t)(bm * 128 + 64 + w * 16 + srow) * K + scol;
  const u16* Wg0 = W + (size_t)(bn * BN +       w * 16 + srow) * K + scol;
  const u16* Wg1 = W + (size_t)(bn * BN + 64 +  w * 16 + srow) * K + scol; // BNFR==4 only
  u16* As0 = &As[w * 512];
  u16* As1 = &As[2048 + w * 512];
  u16* Bs0 = &Bs[w * 512];
  u16* Bs1 = &Bs[2048 + w * 512];

  floatx4 acc[4][BNFR];
  #pragma unroll
  for (int i = 0; i < 4; ++i)
    #pragma unroll
    for (int j = 0; j < BNFR; ++j) acc[i][j] = (floatx4){0.f, 0.f, 0.f, 0.f};

  const int arow = wr * 64 + (lane & 15);
  const int brow = wc * (BNFR * 16) + (lane & 15);
  const int kcol = (lane >> 4) * 8;

  for (int k0 = 0; k0 < K; k0 += 32){
    __syncthreads();
    gload16(Ag0, As0);
    gload16(Ag1, As1);
    gload16(Wg0, Bs0);
    if (BNFR == 4) gload16(Wg1, Bs1);
    Ag0 += 32; Ag1 += 32; Wg0 += 32; Wg1 += 32;
    __syncthreads();
    short8 bf[BNFR];
    #pragma unroll
    for (int ni = 0; ni < BNFR; ++ni)
      bf[ni] = *(const short8*)&Bs[(brow + ni * 16) * 32 + kcol];
    #pragma unroll
    for (int mi = 0; mi < 4; ++mi){
      short8 af = *(const short8*)&As[(arow + mi * 16) * 32 + kcol];
      #pragma unroll
      for (int ni = 0; ni < BNFR; ++ni)
        acc[mi][ni] = __builtin_amdgcn_mfma_f32_16x16x32_bf16(af, bf[ni], acc[mi][ni], 0, 0, 0);
    }
  }

  const int crow = bm * 128 + wr * 64 + (lane >> 4) * 4;
  const int ccol = bn * BN + wc * (BNFR * 16) + (lane & 15);
  #pragma unroll
  for (int mi = 0; mi < 4; ++mi)
    #pragma unroll
    for (int ni = 0; ni < BNFR; ++ni)
      #pragma unroll
      for (int r = 0; r < 4; ++r){
        size_t idx = (size_t)(crow + mi * 16 + r) * N + ccol + ni * 16;
        if (OUTF32) ((float*)C)[idx] = acc[mi][ni][r];
        else        ((u16*)C)[idx]   = f2bf(acc[mi][ni][r]);
      }
}

// fused projections: 1280 blocks; 1-in-5 interleave -> qh (256 blocks), rest -> khv (1024 blocks)
__global__ __launch_bounds__(256) void k_proj(const u16* __restrict__ q_bf, const u16* __restrict__ wq_b,
                                              u16* __restrict__ qh, const u16* __restrict__ c_bf,
                                              const u16* __restrict__ wkv, u16* __restrict__ khv){
  const int sw = (blockIdx.x & 7) * 160 + (blockIdx.x >> 3);   // XCD swizzle over 1280
  const int d5 = sw / 5;
  if (sw - d5 * 5 == 0) gemm_body<0, 4>(q_bf, wq_b, qh, 4096, 1024, 1024, d5);
  else                  gemm_body<0, 4>(c_bf, wkv, khv, 8192, 2048, 1024, sw - 1 - d5);
}

// standalone GEMM (output projection)
template<int OUTF32, int BNFR>
__global__ __launch_bounds__(256) void k_gemm_bt(const u16* __restrict__ A, const u16* __restrict__ W,
                                                 void* __restrict__ C, int M, int N, int K){
  const int nb = (blockIdx.x & 7) * (gridDim.x >> 3) + (blockIdx.x >> 3);
  gemm_body<OUTF32, BNFR>(A, W, C, M, N, K, nb);
}

// ------------- vh rows (t*2+b) stride rs -> vhT [(b*16+h)*64+d][4096 t] -------------
__global__ __launch_bounds__(256) void k_transpose_v(const u16* __restrict__ vh, int rs,
                                                     u16* __restrict__ vhT){
  __shared__ u16 Ts[64 * 64];
  const int bid = blockIdx.x;
  const int tt = bid & 63;
  const int ot = (bid >> 6) & 15;
  const int b  = bid >> 10;
  const int tid = threadIdx.x;

  #pragma unroll
  for (int it = 0; it < 2; ++it){
    int li = tid + it * 256;
    int rt = li >> 3, c8 = li & 7;
    short8 v = *(const short8*)&vh[(size_t)((tt * 64 + rt) * 2 + b) * rs + ot * 64 + c8 * 8];
    int byteoff = (rt * 128 + c8 * 16) ^ ((rt & 7) << 4);
    *(short8*)((char*)Ts + byteoff) = v;
  }
  __syncthreads();

  const int ro = tid & 63, cg = tid >> 6;
  short8 x0, x1;
  #pragma unroll
  for (int tj = 0; tj < 8; ++tj){
    int trow = cg * 16 + tj;
    x0[tj] = (short)*(const u16*)((char*)Ts + ((trow * 128 + ro * 2) ^ ((trow & 7) << 4)));
  }
  #pragma unroll
  for (int tj = 0; tj < 8; ++tj){
    int trow = cg * 16 + 8 + tj;
    x1[tj] = (short)*(const u16*)((char*)Ts + ((trow * 128 + ro * 2) ^ ((trow & 7) << 4)));
  }
  u16* dst = &vhT[(size_t)(b * 1024 + ot * 64 + ro) * 4096 + tt * 64 + cg * 16];
  *(short8*)dst       = x0;
  *(short8*)(dst + 8) = x1;
}

// ------------- flash attention: 8 waves (qi,kj), CHUNK=128 keys, double-buffered LDS -------------
// qh[4096][1024] (pre-scaled by 0.125*log2e), kh rows (t*2+b) stride 2048 (cols 0..1023 of khv),
// vt[2048][4096] -> av[4096][1024]
// Wave (qi = w&3, kj = w>>2): 32 q-rows x 64-key half of each 128-key chunk.
// S^T = mfma(K, Q); P^T -> PV B-frags via permlane32/16_swap; no-max softmax, additive across kj.
// Double buffer: ONE barrier per chunk. K-frags read inline (no hoist: VGPR pressure, round-5 lesson).
__global__ __launch_bounds__(512) void k_attn(const u16* __restrict__ qh, const u16* __restrict__ kh,
                                              const u16* __restrict__ vt, u16* __restrict__ av){
  // buf p (32 KB each): Ks [128k][64d] at byte 0; Vs [64d][128k] at byte 16384
  __shared__ __align__(16) u16 smem[2 * 16384];
  __shared__ float LsX[4][2][64];
  const int tid = threadIdx.x, lane = tid & 63, w = tid >> 6;
  const int qi = w & 3, kj = w >> 2;
  const int g = lane >> 4, q = lane & 15;
  const int nb = (blockIdx.x & 7) * 64 + (blockIdx.x >> 3);  // XCD swizzle (512 blocks)
  const int bh = nb >> 4, qt = nb & 15;
  const int b = bh >> 4, h = bh & 15;

  // Q as B-operand: lane holds col q, dh = kk*32 + g*8 + e
  short8 qf[2][2];
  #pragma unroll
  for (int rf = 0; rf < 2; ++rf){
    int row_l = qt * 128 + qi * 32 + rf * 16 + q;
    #pragma unroll
    for (int kk = 0; kk < 2; ++kk)
      qf[rf][kk] = *(const short8*)&qh[(size_t)(row_l * 2 + b) * 1024 + h * 64 + kk * 32 + g * 8];
  }

  floatx4 o[2][4];
  #pragma unroll
  for (int rf = 0; rf < 2; ++rf)
    #pragma unroll
    for (int dj = 0; dj < 4; ++dj) o[rf][dj] = (floatx4){0.f, 0.f, 0.f, 0.f};
  float ls0 = 0.f, ls1 = 0.f;

  // hoisted swizzled byte offsets (within a buf)
  // K read: row jr = kj*64 + t4*16 + q (128B rows, XOR (q&7)<<4)
  // V read: row dr = t4*16 + q (256B rows at byte 16384+, XOR q<<4)
  int offA[4][2], offB[4][2];
  #pragma unroll
  for (int t4 = 0; t4 < 4; ++t4)
    #pragma unroll
    for (int kk = 0; kk < 2; ++kk){
      offA[t4][kk] = kj * 8192 + (((t4 * 16 + q) * 128 + kk * 64 + g * 16) ^ ((q & 7) << 4));
      offB[t4][kk] = 16384 + (((t4 * 16 + q) * 256 + kj * 128 + kk * 64 + g * 16) ^ (q << 4));
    }

  // staging maps (all 512 threads)
  const int krow = tid >> 3, kc8 = tid & 7;    // K: rows krow, krow+64
  const int vrow = tid >> 4, vc16 = tid & 15;  // V: rows vrow, vrow+32
  const int kwb0 = (((krow)      * 128 + kc8 * 16) ^ ((krow & 7) << 4));
  const int kwb1 = (((krow + 64) * 128 + kc8 * 16) ^ ((krow & 7) << 4));
  const int vwb0 = 16384 + (((vrow)      * 256 + vc16 * 16) ^ ((vrow & 15) << 4));
  const int vwb1 = 16384 + (((vrow + 32) * 256 + vc16 * 16) ^ ((vrow & 15) << 4));
  const u16* kg = kh + (size_t)b * 2048 + h * 64 + kc8 * 8;   // t stride = 4096 u16
  const u16* vg = vt + (size_t)(bh * 64) * 4096 + vc16 * 8;

  // prologue: chunk 0 -> buf0; chunk 1 -> regs
  short8 ka0 = *(const short8*)(kg + (size_t)(krow)      * 4096);
  short8 ka1 = *(const short8*)(kg + (size_t)(krow + 64) * 4096);
  short8 va0 = *(const short8*)(vg + (size_t)(vrow)      * 4096);
  short8 va1 = *(const short8*)(vg + (size_t)(vrow + 32) * 4096);
  {
    char* b0 = (char*)smem;
    *(short8*)(b0 + kwb0) = ka0;
    *(short8*)(b0 + kwb1) = ka1;
    *(short8*)(b0 + vwb0) = va0;
    *(short8*)(b0 + vwb1) = va1;
  }
  ka0 = *(const short8*)(kg + (size_t)(128 + krow)      * 4096);
  ka1 = *(const short8*)(kg + (size_t)(128 + krow + 64) * 4096);
  va0 = *(const short8*)(vg + (size_t)(vrow)      * 4096 + 128);
  va1 = *(const short8*)(vg + (size_t)(vrow + 32) * 4096 + 128);
  __syncthreads();

  for (int ch = 0; ch < 32; ++ch){
    const int base = (ch & 1) << 15;
    const char* bp = (const char*)smem + base;
    char* bq = (char*)smem + (base ^ 32768);

    // stage chunk ch+1 into the other buffer (safe: barrier at end of ch-1 covered reads of bq)
    if (ch < 31){
      *(short8*)(bq + kwb0) = ka0;
      *(short8*)(bq + kwb1) = ka1;
      *(short8*)(bq + vwb0) = va0;
      *(short8*)(bq + vwb1) = va1;
    }

    // S^T = K @ Q  (K-frags read inline: 2 live short8, not 8)
    floatx4 st[2][4];
    #pragma unroll
    for (int rf = 0; rf < 2; ++rf)
      #pragma unroll
      for (int cj = 0; cj < 4; ++cj) st[rf][cj] = (floatx4){0.f, 0.f, 0.f, 0.f};
    __builtin_amdgcn_s_setprio(1);
    #pragma unroll
    for (int cj = 0; cj < 4; ++cj)
      #pragma unroll
      for (int kk = 0; kk < 2; ++kk){
        short8 kf = *(const short8*)(bp + offA[cj][kk]);
        st[0][cj] = __builtin_amdgcn_mfma_f32_16x16x32_bf16(kf, qf[0][kk], st[0][cj], 0, 0, 0);
        st[1][cj] = __builtin_amdgcn_mfma_f32_16x16x32_bf16(kf, qf[1][kk], st[1][cj], 0, 0, 0);
      }
    __builtin_amdgcn_s_setprio(0);

    // issue global loads for chunk ch+2 (after QK: ds_writes above have drained, no WAR stall)
    if (ch < 30){
      const size_t t2 = (size_t)(ch + 2) * 128;
      ka0 = *(const short8*)(kg + (t2 + krow)      * 4096);
      ka1 = *(const short8*)(kg + (t2 + krow + 64) * 4096);
      va0 = *(const short8*)(vg + (size_t)(vrow)      * 4096 + t2);
      va1 = *(const short8*)(vg + (size_t)(vrow + 32) * 4096 + t2);
    }

    // no-max softmax: P = exp2(S), per-lane partial sums; pack bf16 pairs
    unsigned int xw[2][4][2];
    #pragma unroll
    for (int rf = 0; rf < 2; ++rf){
      float rs = 0.f;
      #pragma unroll
      for (int cj = 0; cj < 4; ++cj){
        float p0 = EXP2(st[rf][cj][0]);
        float p1 = EXP2(st[rf][cj][1]);
        float p2 = EXP2(st[rf][cj][2]);
        float p3 = EXP2(st[rf][cj][3]);
        rs += (p0 + p1) + (p2 + p3);
        xw[rf][cj][0] = cvtpk(p0, p1);
        xw[rf][cj][1] = cvtpk(p2, p3);
      }
      if (rf == 0) ls0 += rs; else ls1 += rs;
    }

    // register P^T exchange -> PV B-frags (lane&15 preserved)
    uint32x4 pb[2][2];
    #pragma unroll
    for (int rf = 0; rf < 2; ++rf)
      #pragma unroll
      for (int kk = 0; kk < 2; ++kk)
        #pragma unroll
        for (int wd = 0; wd < 2; ++wd){
          unsigned int aa = xw[rf][2 * kk][wd], bb = xw[rf][2 * kk + 1][wd];
          asm("v_permlane32_swap_b32 %0, %1" : "+v"(aa), "+v"(bb));
          asm("v_permlane16_swap_b32 %0, %1" : "+v"(aa), "+v"(bb));
          pb[rf][kk][wd]     = aa;
          pb[rf][kk][wd + 2] = bb;
        }

    // O^T += V^T @ P^T
    __builtin_amdgcn_s_setprio(1);
    #pragma unroll
    for (int kk = 0; kk < 2; ++kk){
      short8 pb0 = __builtin_bit_cast(short8, pb[0][kk]);
      short8 pb1 = __builtin_bit_cast(short8, pb[1][kk]);
      #pragma unroll
      for (int dj = 0; dj < 4; ++dj){
        short8 vf = *(const short8*)(bp + offB[dj][kk]);
        o[0][dj] = __builtin_amdgcn_mfma_f32_16x16x32_bf16(vf, pb0, o[0][dj], 0, 0, 0);
        o[1][dj] = __builtin_amdgcn_mfma_f32_16x16x32_bf16(vf, pb1, o[1][dj], 0, 0, 0);
      }
    }
    __builtin_amdgcn_s_setprio(0);

    __syncthreads();   // single barrier per chunk
  }

  // combine kj halves: partial O and l are directly additive (no-max softmax)
  if (kj == 1){
    #pragma unroll
    for (int rf = 0; rf < 2; ++rf)
      #pragma unroll
      for (int dj = 0; dj < 4; ++dj){
        int idx = rf * 4 + dj;
        *(floatx4*)((char*)smem + qi * 8192 + ((lane * 128 + idx * 16) ^ ((lane & 7) << 4))) = o[rf][dj];
      }
    LsX[qi][0][lane] = ls0;
    LsX[qi][1][lane] = ls1;
  }
  __syncthreads();
  if (kj == 0){
    #pragma unroll
    for (int rf = 0; rf < 2; ++rf)
      #pragma unroll
      for (int dj = 0; dj < 4; ++dj){
        int idx = rf * 4 + dj;
        o[rf][dj] += *(const floatx4*)((char*)smem + qi * 8192 + ((lane * 128 + idx * 16) ^ ((lane & 7) << 4)));
      }
    ls0 += LsX[qi][0][lane];
    ls1 += LsX[qi][1][lane];
    ls0 += __shfl_xor(ls0, 16, 64);
    ls0 += __shfl_xor(ls0, 32, 64);
    ls1 += __shfl_xor(ls1, 16, 64);
    ls1 += __shfl_xor(ls1, 32, 64);
    #pragma unroll
    for (int rf = 0; rf < 2; ++rf){
      float inv = 1.0f / (rf == 0 ? ls0 : ls1);
      int row_l = qt * 128 + qi * 32 + rf * 16 + q;
      u16* dst = av + (size_t)(row_l * 2 + b) * 1024 + h * 64 + 4 * g;
      #pragma unroll
      for (int dj = 0; dj < 4; ++dj){
        uint32x2 pk;
        pk[0] = cvtpk(o[rf][dj][0] * inv, o[rf][dj][1] * inv);
        pk[1] = cvtpk(o[rf][dj][2] * inv, o[rf][dj][3] * inv);
        *(uint32x2*)(dst + dj * 16) = pk;
      }
    }
  }
}

// --------------------------------- launch ---------------------------------
extern "C" void kernel_launch(void* const* d_in, const int* in_sizes, int n_in,
                              void* d_out, int out_size, void* d_ws, size_t ws_size,
                              hipStream_t stream){
  const float* q    = (const float*)d_in[0];
  const float* kv   = (const float*)d_in[1];
  const float* mems = (const float*)d_in[2];
  const float* wq   = (const float*)d_in[3];
  const float* wk   = (const float*)d_in[4];
  const float* wv   = (const float*)d_in[5];
  const float* wc   = (const float*)d_in[6];

  const size_t SZ_Q  = (size_t)4096 * 1024;   // L*B x D
  const size_t SZ_C  = (size_t)8192 * 1024;   // (M+L)*B x D
  const size_t SZ_W  = (size_t)1024 * 1024;
  const size_t SZ_KV = (size_t)8192 * 2048;   // fused K|V projection output

  u16* ws   = (u16*)d_ws;
  u16* q_bf = ws;                 // later reused as attn_vec (av)
  u16* c_bf = q_bf + SZ_Q;        // later reused as vhT (8M elem: exact fit)
  u16* wq_b = c_bf + SZ_C;
  u16* wk_b = wq_b + SZ_W;        // wk_b and wv_b adjacent -> fused W_kv [2048][1024]
  u16* wv_b = wk_b + SZ_W;
  u16* wc_b = wv_b + SZ_W;
  u16* qh   = wc_b + SZ_W;
  u16* khv  = qh + SZ_Q;          // [8192][2048]: cols 0..1023 = kh, 1024..2047 = vh

  // fused casts; attention scale 1/8 AND log2e folded into w_q
  Cast7 ca;
  ca.s[0] = { q,    q_bf,        (int)(SZ_Q / 8), 1.0f };
  ca.s[1] = { mems, c_bf,        (int)(SZ_Q / 8), 1.0f };
  ca.s[2] = { kv,   c_bf + SZ_Q, (int)(SZ_Q / 8), 1.0f };
  ca.s[3] = { wq,   wq_b,        (int)(SZ_W / 8), 0.125f * LOG2E };
  ca.s[4] = { wk,   wk_b,        (int)(SZ_W / 8), 1.0f };
  ca.s[5] = { wv,   wv_b,        (int)(SZ_W / 8), 1.0f };
  ca.s[6] = { wc,   wc_b,        (int)(SZ_W / 8), 1.0f };
  k_cast_all<<<2048, 256, 0, stream>>>(ca);

  // fused projections: q -> qh AND c -> [kh | vh], one 1280-block launch (128^2 tiles)
  k_proj<<<1280, 256, 0, stream>>>(q_bf, wq_b, qh, c_bf, wk_b, khv);

  // V part of khv -> vhT [(b*16+h)*64+d][t]
  k_transpose_v<<<2048, 256, 0, stream>>>(khv + 1024, 2048, c_bf);

  // flash attention -> av (8 waves: 4 q-subtiles x 2 key-halves, double-buffered)
  k_attn<<<512, 512, 0, stream>>>(qh, khv, c_bf, q_bf);

  // out = attn_vec @ w_concat^T  (fp32 out)
  k_gemm_bt<1, 2><<<512, 256, 0, stream>>>(q_bf, wc_b, d_out, 4096, 1024, 1024);
}